// Round 12
// baseline (178.531 us; speedup 1.0000x reference)
//
#include <hip/hip_runtime.h>

// Problem shapes (fixed by reference setup_inputs)
#define B_DIM 1024
#define C_DIM 128
#define K_DIM 1024
#define E_DIM 4
#define EMBED_ELEMS (B_DIM * C_DIM * E_DIM)
#define OH_ELEMS ((size_t)B_DIM * C_DIM * K_DIM)   // 134,217,728 dwords

typedef float f32x4 __attribute__((ext_vector_type(4)));

// ---------------------------------------------------------------------------
// K_fused: argmin + embed (proven-exact f64 path, unchanged) PLUS a
// GRID-STRIDE zero-fill of the one-hot output (32 f32x4 stores/thread,
// 16 MB-advancing monotonic window — the measured-fastest store pattern).
// Stores are fire-and-forget and drain during the f64 scan.
// Grid = 4096 blocks: covers all (b,c) rows AND all 512 MB of zeros.
// ---------------------------------------------------------------------------
__global__ __launch_bounds__(256) void vq_fused_kernel(
    const float* __restrict__ cw_q,      // (B, C*E) f32
    const float* __restrict__ codebook,  // (C, K, E) f32
    float* __restrict__ out,             // [embed | one_hot]
    int* __restrict__ idx_out)           // (B, C) int32 in d_ws
{
    __shared__ float4 lds_cb[K_DIM];     // 16 KB: codebook[c]

    const int lane = threadIdx.x & 63;
    const int wave = threadIdx.x >> 6;
    const int bid  = blockIdx.x;
    const int c      = bid >> 5;         // 32 blocks per c
    const int btile  = bid & 31;
    const int b_base = btile * 32 + wave * 8;

    const float4* cb4 = (const float4*)codebook + (size_t)c * K_DIM;
    const float4* x4  = (const float4*)cw_q;    // (B, C) float4
    float4* emb4 = (float4*)out;                // (B, C) float4

    // 1) Stage codebook into LDS.
    for (int t = threadIdx.x; t < K_DIM; t += 256)
        lds_cb[t] = cb4[t];

    // 2) Load this wave's 8 x-rows BEFORE the store burst.
    float4 xr[8];
#pragma unroll
    for (int i = 0; i < 8; ++i)
        xr[i] = x4[(size_t)(b_base + i) * C_DIM + c];

    __syncthreads();

    // 3) Zero-fill burst: GRID-STRIDE, pure store stream (no loads).
    //    elem = i*1M + bid*256 + tid ; 4096*256*32 = 32M f32x4 = 512 MB.
    {
        f32x4* dst = (f32x4*)(out + EMBED_ELEMS)
                   + (size_t)bid * 256 + threadIdx.x;
        const f32x4 z = {0.f, 0.f, 0.f, 0.f};
#pragma unroll
        for (int i = 0; i < 32; ++i)
            dst[(size_t)i * (4096 * 256)] = z;
    }

    // 4) ||b_k||^2 in f64 (exact from f32 inputs -> true ordering, R3-proven).
    double bsq[16];
#pragma unroll
    for (int j = 0; j < 16; ++j) {
        const float4 cb = lds_cb[j * 64 + lane];
        const double bx = (double)cb.x, by = (double)cb.y,
                     bz = (double)cb.z, bw = (double)cb.w;
        bsq[j] = bx * bx + by * by + bz * bz + bw * bw;
    }

    // 5) Argmin scan, 2 groups of 4 rows (overlaps the store drain).
    for (int g = 0; g < 2; ++g) {
        double x2[4][4];
#pragma unroll
        for (int ii = 0; ii < 4; ++ii) {
            const float4 x = xr[g * 4 + ii];
            x2[ii][0] = -2.0 * (double)x.x;
            x2[ii][1] = -2.0 * (double)x.y;
            x2[ii][2] = -2.0 * (double)x.z;
            x2[ii][3] = -2.0 * (double)x.w;
        }

        double bestd[4];
        int    bestk[4];
#pragma unroll
        for (int ii = 0; ii < 4; ++ii) { bestd[ii] = INFINITY; bestk[ii] = 0x7fffffff; }

        for (int j = 0; j < 16; ++j) {
            const float4 cb = lds_cb[j * 64 + lane];
            const double bx = (double)cb.x, by = (double)cb.y,
                         bz = (double)cb.z, bw = (double)cb.w;
            const int k = j * 64 + lane;
#pragma unroll
            for (int ii = 0; ii < 4; ++ii) {
                // d' = bsq - 2*dot  (x_sq constant over k: argmin-invariant)
                const double d = fma(bw, x2[ii][3],
                                 fma(bz, x2[ii][2],
                                 fma(by, x2[ii][1],
                                 fma(bx, x2[ii][0], bsq[j]))));
                if (d < bestd[ii]) { bestd[ii] = d; bestk[ii] = k; }
            }
        }

        // Wave argmin, lexicographic (d, k), 4 rows interleaved.
#pragma unroll
        for (int off = 32; off >= 1; off >>= 1) {
#pragma unroll
            for (int ii = 0; ii < 4; ++ii) {
                const double od = __shfl_xor(bestd[ii], off);
                const int    oi = __shfl_xor(bestk[ii], off);
                if (od < bestd[ii] || (od == bestd[ii] && oi < bestk[ii])) {
                    bestd[ii] = od; bestk[ii] = oi;
                }
            }
        }

#pragma unroll
        for (int ii = 0; ii < 4; ++ii) {
            const int b  = b_base + g * 4 + ii;
            const int bi = bestk[ii];
            if (lane == 0) {
                emb4[(size_t)b * C_DIM + c] = lds_cb[bi];
                idx_out[b * C_DIM + c]      = bi;   // K_ones reads it
            }
        }
    }
}

// ---------------------------------------------------------------------------
// K_ones: scatter the 131072 ones. One thread per (b*C+c) row.
// Runs after K_fused (kernel boundary orders the zero-fill and idx writes).
// ---------------------------------------------------------------------------
__global__ __launch_bounds__(256) void vq_scatter_ones(
    const int* __restrict__ idx_in,      // (B, C) flat
    float* __restrict__ out)             // one_hot at EMBED_ELEMS
{
    const int r = blockIdx.x * 256 + threadIdx.x;   // flat row, coalesced idx
    const int k = idx_in[r];
    out[EMBED_ELEMS + (size_t)r * K_DIM + k] = 1.0f;
}

extern "C" void kernel_launch(void* const* d_in, const int* in_sizes, int n_in,
                              void* d_out, int out_size, void* d_ws, size_t ws_size,
                              hipStream_t stream) {
    const float* cw_q     = (const float*)d_in[0];
    const float* codebook = (const float*)d_in[1];
    float* out = (float*)d_out;
    int*   idx = (int*)d_ws;   // 512 KB scratch

    vq_fused_kernel<<<C_DIM * (B_DIM / 32), 256, 0, stream>>>(cw_q, codebook, out, idx);
    vq_scatter_ones<<<(B_DIM * C_DIM) / 256, 256, 0, stream>>>(idx, out);
}

// Round 13
// 144.902 us; speedup vs baseline: 1.2321x; 1.2321x over previous
//
#include <hip/hip_runtime.h>

// Problem shapes (fixed by reference setup_inputs)
#define B_DIM 1024
#define C_DIM 128
#define K_DIM 1024
#define E_DIM 4
#define EMBED_ELEMS (B_DIM * C_DIM * E_DIM)

typedef float f32x4 __attribute__((ext_vector_type(4)));

// ---------------------------------------------------------------------------
// K_fused: argmin + embed (proven-exact f64 path) with the 128 KB/block
// zero-fill PACED through the compute: exactly one f32x4 store per
// j-iteration (32 slots = 32 stores), so store-issue never outruns the
// drain and compute cycles fill the gaps.
// Grid = 4096 blocks: covers all (b,c) rows AND all 512 MB of zeros.
// ---------------------------------------------------------------------------
__global__ __launch_bounds__(256) void vq_fused_kernel(
    const float* __restrict__ cw_q,      // (B, C*E) f32
    const float* __restrict__ codebook,  // (C, K, E) f32
    float* __restrict__ out,             // [embed | one_hot]
    int* __restrict__ idx_out)           // (B, C) int32 in d_ws
{
    __shared__ float4 lds_cb[K_DIM];     // 16 KB: codebook[c]

    const int lane = threadIdx.x & 63;
    const int wave = threadIdx.x >> 6;
    const int bid  = blockIdx.x;
    const int c      = bid >> 5;         // 32 blocks per c
    const int btile  = bid & 31;
    const int b_base = btile * 32 + wave * 8;

    const float4* cb4 = (const float4*)codebook + (size_t)c * K_DIM;
    const float4* x4  = (const float4*)cw_q;    // (B, C) float4
    float4* emb4 = (float4*)out;                // (B, C) float4

    // Zero-fill destination: 128 KB contiguous per block (blocked layout).
    f32x4* zdst = (f32x4*)(out + EMBED_ELEMS) + (size_t)bid * 8192
                + threadIdx.x;
    const f32x4 zval = {0.f, 0.f, 0.f, 0.f};

    // 1) Stage codebook into LDS.
    for (int t = threadIdx.x; t < K_DIM; t += 256)
        lds_cb[t] = cb4[t];

    // 2) Load this wave's 8 x-rows up front.
    float4 xr[8];
#pragma unroll
    for (int i = 0; i < 8; ++i)
        xr[i] = x4[(size_t)(b_base + i) * C_DIM + c];

    __syncthreads();

    // 3) ||b_k||^2 in f64 (exact from f32 inputs -> true ordering, R3-proven).
    double bsq[16];
#pragma unroll
    for (int j = 0; j < 16; ++j) {
        const float4 cb = lds_cb[j * 64 + lane];
        const double bx = (double)cb.x, by = (double)cb.y,
                     bz = (double)cb.z, bw = (double)cb.w;
        bsq[j] = bx * bx + by * by + bz * bz + bw * bw;
    }

    // 4) Argmin scan, 2 groups of 4 rows; one zero store paced per j-iter.
    for (int g = 0; g < 2; ++g) {
        double x2[4][4];
#pragma unroll
        for (int ii = 0; ii < 4; ++ii) {
            const float4 x = xr[g * 4 + ii];
            x2[ii][0] = -2.0 * (double)x.x;
            x2[ii][1] = -2.0 * (double)x.y;
            x2[ii][2] = -2.0 * (double)x.z;
            x2[ii][3] = -2.0 * (double)x.w;
        }

        double bestd[4];
        int    bestk[4];
#pragma unroll
        for (int ii = 0; ii < 4; ++ii) { bestd[ii] = INFINITY; bestk[ii] = 0x7fffffff; }

#pragma unroll 1   // keep one store per iteration — do NOT re-cluster
        for (int j = 0; j < 16; ++j) {
            // paced zero store: slot g*16+j of 32
            zdst[(g * 16 + j) * 256] = zval;

            const float4 cb = lds_cb[j * 64 + lane];
            const double bx = (double)cb.x, by = (double)cb.y,
                         bz = (double)cb.z, bw = (double)cb.w;
            const int k = j * 64 + lane;
#pragma unroll
            for (int ii = 0; ii < 4; ++ii) {
                // d' = bsq - 2*dot  (x_sq constant over k: argmin-invariant)
                const double d = fma(bw, x2[ii][3],
                                 fma(bz, x2[ii][2],
                                 fma(by, x2[ii][1],
                                 fma(bx, x2[ii][0], bsq[j]))));
                if (d < bestd[ii]) { bestd[ii] = d; bestk[ii] = k; }
            }
        }

        // Wave argmin, lexicographic (d, k), 4 rows interleaved.
#pragma unroll
        for (int off = 32; off >= 1; off >>= 1) {
#pragma unroll
            for (int ii = 0; ii < 4; ++ii) {
                const double od = __shfl_xor(bestd[ii], off);
                const int    oi = __shfl_xor(bestk[ii], off);
                if (od < bestd[ii] || (od == bestd[ii] && oi < bestk[ii])) {
                    bestd[ii] = od; bestk[ii] = oi;
                }
            }
        }

#pragma unroll
        for (int ii = 0; ii < 4; ++ii) {
            const int b  = b_base + g * 4 + ii;
            const int bi = bestk[ii];
            if (lane == 0) {
                emb4[(size_t)b * C_DIM + c] = lds_cb[bi];
                idx_out[b * C_DIM + c]      = bi;   // K_ones reads it
            }
        }
    }
}

// ---------------------------------------------------------------------------
// K_ones: scatter the 131072 ones. One thread per (b*C+c) row.
// Runs after K_fused (kernel boundary orders the zero-fill and idx writes).
// ---------------------------------------------------------------------------
__global__ __launch_bounds__(256) void vq_scatter_ones(
    const int* __restrict__ idx_in,      // (B, C) flat
    float* __restrict__ out)             // one_hot at EMBED_ELEMS
{
    const int r = blockIdx.x * 256 + threadIdx.x;   // flat row, coalesced idx
    const int k = idx_in[r];
    out[EMBED_ELEMS + (size_t)r * K_DIM + k] = 1.0f;
}

extern "C" void kernel_launch(void* const* d_in, const int* in_sizes, int n_in,
                              void* d_out, int out_size, void* d_ws, size_t ws_size,
                              hipStream_t stream) {
    const float* cw_q     = (const float*)d_in[0];
    const float* codebook = (const float*)d_in[1];
    float* out = (float*)d_out;
    int*   idx = (int*)d_ws;   // 512 KB scratch

    vq_fused_kernel<<<C_DIM * (B_DIM / 32), 256, 0, stream>>>(cw_q, codebook, out, idx);
    vq_scatter_ones<<<(B_DIM * C_DIM) / 256, 256, 0, stream>>>(idx, out);
}